// Round 8
// baseline (234.289 us; speedup 1.0000x reference)
//
#include <hip/hip_runtime.h>
#include <hip/hip_bf16.h>
#include <cstdint>
#include <cmath>

#define SQL 2048
#define SKVL 2048
#define DD 128
#define NB 16
#define QBLK 64
#define KVB 64
#define NT (SKVL / KVB)

typedef __attribute__((ext_vector_type(8))) short short8;
typedef __attribute__((ext_vector_type(4))) float f32x4;

__device__ __forceinline__ ushort f2bf(float x) {
    union { float f; uint32_t u; } v; v.f = x;
    uint32_t r = v.u + 0x7FFFu + ((v.u >> 16) & 1u);
    return (ushort)(r >> 16);
}

// fp32 -> bf16 with scale folded in; 8 elements/thread. (Used for Q.)
__global__ void convert_scale_k(const float* __restrict__ in, ushort* __restrict__ out, float scale) {
    size_t i = (size_t)blockIdx.x * blockDim.x + threadIdx.x;
    const f32x4* p = (const f32x4*)in + i * 2;
    f32x4 a = p[0], b = p[1];
    short8 o;
    o[0] = (short)f2bf(a[0] * scale);
    o[1] = (short)f2bf(a[1] * scale);
    o[2] = (short)f2bf(a[2] * scale);
    o[3] = (short)f2bf(a[3] * scale);
    o[4] = (short)f2bf(b[0] * scale);
    o[5] = (short)f2bf(b[1] * scale);
    o[6] = (short)f2bf(b[2] * scale);
    o[7] = (short)f2bf(b[3] * scale);
    *((short8*)out + i) = o;
}

// K fp32 [B][SKV][128] -> tiled swizzled bf16 [B][SKV/64][64 rows x 128 cols].
// Within a 16KB tile: elem (r,c) -> r*128 + ((c>>3)^(r&7))*8 + (c&7).
__global__ void convert_k_tiled(const float* __restrict__ in, ushort* __restrict__ out) {
    int gid = blockIdx.x * blockDim.x + threadIdx.x;   // one 16B out-chunk (8 elems)
    int c16 = gid & 15;
    int rg  = gid >> 4;            // b*SKV + kv
    int r   = rg & 63;
    int tile = rg >> 6;            // b*32 + kt
    const f32x4* p = (const f32x4*)(in + (size_t)rg * DD + c16 * 8);
    f32x4 a = p[0], b = p[1];
    short8 o;
    o[0] = (short)f2bf(a[0]); o[1] = (short)f2bf(a[1]);
    o[2] = (short)f2bf(a[2]); o[3] = (short)f2bf(a[3]);
    o[4] = (short)f2bf(b[0]); o[5] = (short)f2bf(b[1]);
    o[6] = (short)f2bf(b[2]); o[7] = (short)f2bf(b[3]);
    int cs = c16 ^ (r & 7);
    *(short8*)(out + ((size_t)tile << 13) + r * 128 + cs * 8) = o;
}

// V fp32 [B][SKV][128] -> V^T tiled bf16 [B][SKV/64][128 d-rows x 8 chunks].
// kv permuted to the PV mfma slot map (NO bank swizzle -- read from global):
// chunk cs (= h*4+g) elem j -> kv = h*32 + g*4 + (j&3) + 16*(j>>2).
__global__ void convert_vt_tiled(const float* __restrict__ v, ushort* __restrict__ vt) {
    __shared__ float tile[64][129];
    int bid = blockIdx.x;          // b*32 + kt
    int kt = bid & 31;
    int b  = bid >> 5;
    int tx = threadIdx.x & 63, ty = threadIdx.x >> 6;  // 64 x 4
    const float* src = v + ((size_t)b * SKVL + (size_t)kt * 64) * DD;
#pragma unroll
    for (int r = ty; r < 64; r += 4) {
        tile[r][tx * 2]     = src[(size_t)r * DD + tx * 2];
        tile[r][tx * 2 + 1] = src[(size_t)r * DD + tx * 2 + 1];
    }
    __syncthreads();
    ushort* dst = vt + ((size_t)bid << 13);
#pragma unroll
    for (int i = 0; i < 4; ++i) {
        int q = threadIdx.x + 256 * i;   // 1024 chunks: d(128) x cs(8)
        int d = q >> 3;
        int cs = q & 7;
        int h = cs >> 2, g = cs & 3;
        short8 o;
#pragma unroll
        for (int j = 0; j < 8; ++j) {
            int kv = h * 32 + g * 4 + (j & 3) + 16 * (j >> 2);
            o[j] = (short)f2bf(tile[kv][d]);
        }
        *(short8*)(dst + d * 64 + cs * 8) = o;
    }
}

#define GLD_LDS16(gsrc, ldst) \
    __builtin_amdgcn_global_load_lds((const __attribute__((address_space(1))) uint32_t*)(gsrc), \
                                     (__attribute__((address_space(3))) uint32_t*)(ldst), 16, 0, 0)

// Flash attention fwd. Grid = B * SQ/64 = 512 blocks, 256 thr (4 waves).
// K double-buffered in LDS (32KB) via global_load_lds; V^T fragments read
// per-lane DIRECTLY from the pre-permuted workspace (L2-resident), issued at
// tile start so QK^T+softmax hides the latency (halves LDS-pipe traffic).
__global__ __launch_bounds__(256, 2) void fattn(
    const ushort* __restrict__ qb, const ushort* __restrict__ kbt,
    const ushort* __restrict__ vbt, float* __restrict__ out)
{
    __shared__ short8 kls[2][1024];   // [buf][r*16 + chunk] 16KB x2

    int bid = blockIdx.x;
    // XCD-bijective swizzle: 512 = 8 XCDs x 64 -> 2 batches' K/V per XCD L2.
    int swz = (bid & 7) * 64 + (bid >> 3);
    int b  = swz >> 5;
    int qt = swz & 31;
    int lane = threadIdx.x & 63;
    int w = threadIdx.x >> 6;
    int g = lane >> 4;
    int qi = lane & 15;
    int rx = qi & 7;
    int qrow = qt * QBLK + w * 16 + qi;

    const ushort* ktile0 = kbt + ((size_t)(b * NT) << 13);
    // per-lane V base: chunk (h*4+g) of d-row (dt*16+qi); vlp in short8 units
    const short8* vlp = (const short8*)vbt + ((size_t)(b * NT) << 10) + qi * 8 + g;

    // Q fragments: lane holds q=qi, d-slots ks*32 + g*8 + j.
    const ushort* qptr = qb + ((size_t)b * SQL + qrow) * DD;
    short8 qf[4];
#pragma unroll
    for (int ks = 0; ks < 4; ++ks)
        qf[ks] = *(const short8*)(qptr + ks * 32 + g * 8);

    f32x4 acc[8];
#pragma unroll
    for (int i = 0; i < 8; ++i) acc[i] = (f32x4)0.f;
    float m = -1e30f, lsum = 0.f;

    // prologue: stage K tile 0 into buf 0 (each wave copies its 4KB quarter)
#pragma unroll
    for (int i = 0; i < 4; ++i) {
        int off = w * 4096 + i * 1024;
        GLD_LDS16((const char*)ktile0 + off + lane * 16, (char*)&kls[0][0] + off);
    }
    __syncthreads();

    for (int t = 0; t < NT; ++t) {
        int cur = t & 1, nxt = cur ^ 1;
        // ---- issue V(t) per-lane loads FIRST (oldest in vmcnt queue) ----
        short8 vf[16];
#pragma unroll
        for (int dt = 0; dt < 8; ++dt) {
#pragma unroll
            for (int h = 0; h < 2; ++h)
                vf[dt * 2 + h] = vlp[t * 1024 + dt * 128 + h * 4];
        }
        // ---- stage K(t+1); stays in flight across PV (counted vmcnt) ----
        if (t + 1 < NT) {
            const char* ks = (const char*)ktile0 + ((size_t)(t + 1) << 14);
#pragma unroll
            for (int i = 0; i < 4; ++i) {
                int off = w * 4096 + i * 1024;
                GLD_LDS16(ks + off + lane * 16, (char*)&kls[nxt][0] + off);
            }
        }
        // ---- QK^T from LDS: S^T = mfma(K, Q) ----
        f32x4 st[4];
        __builtin_amdgcn_s_setprio(1);
#pragma unroll
        for (int sub = 0; sub < 4; ++sub) {
            f32x4 s = (f32x4)0.f;
            int r = sub * 16 + qi;
#pragma unroll
            for (int ks = 0; ks < 4; ++ks) {
                short8 kf = kls[cur][r * 16 + ((ks * 4 + g) ^ rx)];
                s = __builtin_amdgcn_mfma_f32_16x16x32_bf16(kf, qf[ks], s, 0, 0, 0);
            }
            st[sub] = s;
        }
        __builtin_amdgcn_s_setprio(0);
        // ---- online softmax, defer-max; shfls only on the cold path ----
        float m0 = fmaxf(fmaxf(st[0][0], st[0][1]), fmaxf(st[0][2], st[0][3]));
        float m1 = fmaxf(fmaxf(st[1][0], st[1][1]), fmaxf(st[1][2], st[1][3]));
        float m2 = fmaxf(fmaxf(st[2][0], st[2][1]), fmaxf(st[2][2], st[2][3]));
        float m3 = fmaxf(fmaxf(st[3][0], st[3][1]), fmaxf(st[3][2], st[3][3]));
        float vmax = fmaxf(fmaxf(m0, m1), fmaxf(m2, m3));
        if (__any(vmax > m + 11.5f)) {
            float tmax = fmaxf(vmax, __shfl_xor(vmax, 16));
            tmax = fmaxf(tmax, __shfl_xor(tmax, 32));
            float mnew = fmaxf(m, tmax);
            float alpha = exp2f(m - mnew);
            m = mnew;
            lsum *= alpha;
#pragma unroll
            for (int i = 0; i < 8; ++i) {
                acc[i][0] *= alpha; acc[i][1] *= alpha;
                acc[i][2] *= alpha; acc[i][3] *= alpha;
            }
        }
        float pv[16];
        float ps[4];
#pragma unroll
        for (int s = 0; s < 4; ++s) {
            pv[s * 4 + 0] = exp2f(st[s][0] - m);
            pv[s * 4 + 1] = exp2f(st[s][1] - m);
            pv[s * 4 + 2] = exp2f(st[s][2] - m);
            pv[s * 4 + 3] = exp2f(st[s][3] - m);
            ps[s] = (pv[s * 4 + 0] + pv[s * 4 + 1]) + (pv[s * 4 + 2] + pv[s * 4 + 3]);
        }
        lsum += (ps[0] + ps[1]) + (ps[2] + ps[3]);
        union { short8 v; uint32_t u[4]; } P0, P1;
#pragma unroll
        for (int i = 0; i < 4; ++i) {
            asm("v_cvt_pk_bf16_f32 %0, %1, %2" : "=v"(P0.u[i]) : "v"(pv[2 * i]), "v"(pv[2 * i + 1]));
            asm("v_cvt_pk_bf16_f32 %0, %1, %2" : "=v"(P1.u[i]) : "v"(pv[8 + 2 * i]), "v"(pv[8 + 2 * i + 1]));
        }
        // ---- PV from registers: O^T += V^T * P^T ----
        __builtin_amdgcn_s_setprio(1);
#pragma unroll
        for (int dt = 0; dt < 8; ++dt) {
            acc[dt] = __builtin_amdgcn_mfma_f32_16x16x32_bf16(vf[dt * 2 + 0], P0.v, acc[dt], 0, 0, 0);
            acc[dt] = __builtin_amdgcn_mfma_f32_16x16x32_bf16(vf[dt * 2 + 1], P1.v, acc[dt], 0, 0, 0);
        }
        __builtin_amdgcn_s_setprio(0);
        __syncthreads();   // K(t+1) staged (vmcnt0 drain), reads of cur done
    }

    lsum += __shfl_xor(lsum, 16);
    lsum += __shfl_xor(lsum, 32);
    float inv = 1.f / lsum;
    float* optr = out + ((size_t)b * SQL + qrow) * DD + g * 4;
#pragma unroll
    for (int dt = 0; dt < 8; ++dt) {
        f32x4 o;
        o[0] = acc[dt][0] * inv; o[1] = acc[dt][1] * inv;
        o[2] = acc[dt][2] * inv; o[3] = acc[dt][3] * inv;
        *(f32x4*)(optr + dt * 16) = o;
    }
}

extern "C" void kernel_launch(void* const* d_in, const int* in_sizes, int n_in,
                              void* d_out, int out_size, void* d_ws, size_t ws_size,
                              hipStream_t stream) {
    const float* q = (const float*)d_in[0];
    const float* k = (const float*)d_in[1];
    const float* v = (const float*)d_in[2];
    float* out = (float*)d_out;

    uint8_t* w = (uint8_t*)d_ws;
    size_t tsz = (size_t)NB * SQL * DD * sizeof(ushort);  // 8 MB per tensor
    ushort* qb  = (ushort*)w;
    ushort* kbt = (ushort*)(w + tsz);
    ushort* vbt = (ushort*)(w + 2 * tsz);

    float qscale = 1.4426950408889634f / sqrtf((float)DD);
    int n8 = NB * SQL * DD / 8;
    convert_scale_k<<<n8 / 256, 256, 0, stream>>>(q, qb, qscale);
    convert_k_tiled<<<NB * SKVL * 16 / 256, 256, 0, stream>>>(k, kbt);
    convert_vt_tiled<<<NB * (SKVL / 64), 256, 0, stream>>>(v, vbt);
    fattn<<<NB * (SQL / QBLK), 256, 0, stream>>>(qb, kbt, vbt, out);
}

// Round 9
// 155.770 us; speedup vs baseline: 1.5041x; 1.5041x over previous
//
#include <hip/hip_runtime.h>
#include <hip/hip_bf16.h>
#include <cstdint>
#include <cmath>

#define SQL 2048
#define SKVL 2048
#define DD 128
#define NB 16
#define QBLK 64
#define KVB 32
#define NT 32            // tiles per stream (two streams of 1024 kv each)

typedef __attribute__((ext_vector_type(8))) short short8;
typedef __attribute__((ext_vector_type(4))) float f32x4;

__device__ __forceinline__ ushort f2bf(float x) {
    union { float f; uint32_t u; } v; v.f = x;
    uint32_t r = v.u + 0x7FFFu + ((v.u >> 16) & 1u);
    return (ushort)(r >> 16);
}

// fp32 -> bf16 with scale folded in; 8 elements/thread. (Used for Q.)
__global__ void convert_scale_k(const float* __restrict__ in, ushort* __restrict__ out, float scale) {
    size_t i = (size_t)blockIdx.x * blockDim.x + threadIdx.x;
    const f32x4* p = (const f32x4*)in + i * 2;
    f32x4 a = p[0], b = p[1];
    short8 o;
    o[0] = (short)f2bf(a[0] * scale);
    o[1] = (short)f2bf(a[1] * scale);
    o[2] = (short)f2bf(a[2] * scale);
    o[3] = (short)f2bf(a[3] * scale);
    o[4] = (short)f2bf(b[0] * scale);
    o[5] = (short)f2bf(b[1] * scale);
    o[6] = (short)f2bf(b[2] * scale);
    o[7] = (short)f2bf(b[3] * scale);
    *((short8*)out + i) = o;
}

// K fp32 [B][SKV][128] -> tiled swizzled bf16 [B][SKV/32][32 rows x 128 cols].
// Within an 8KB tile: elem (r,c) -> r*128 + ((c>>3)^(r&7))*8 + (c&7).
__global__ void convert_k_tiled(const float* __restrict__ in, ushort* __restrict__ out) {
    int gid = blockIdx.x * blockDim.x + threadIdx.x;   // one 16B out-chunk (8 elems)
    int c16 = gid & 15;
    int rg  = gid >> 4;            // b*SKV + kv
    int r   = rg & 31;
    int tile = rg >> 5;            // b*64 + kt
    const f32x4* p = (const f32x4*)(in + (size_t)rg * DD + c16 * 8);
    f32x4 a = p[0], b = p[1];
    short8 o;
    o[0] = (short)f2bf(a[0]); o[1] = (short)f2bf(a[1]);
    o[2] = (short)f2bf(a[2]); o[3] = (short)f2bf(a[3]);
    o[4] = (short)f2bf(b[0]); o[5] = (short)f2bf(b[1]);
    o[6] = (short)f2bf(b[2]); o[7] = (short)f2bf(b[3]);
    int cs = c16 ^ (r & 7);
    *(short8*)(out + ((size_t)tile << 12) + r * 128 + cs * 8) = o;
}

// V fp32 [B][SKV][128] -> V^T tiled bf16 [B][SKV/32][128 d-rows x 32 kv].
// kv permuted to the PV mfma slot map: logical chunk cs elem j -> kv =
// (j>>2)*16 + cs*4 + (j&3); storage chunk cs' = cs ^ ((d>>1)&3) (XOR swizzle).
__global__ void convert_vt_tiled(const float* __restrict__ v, ushort* __restrict__ vt) {
    __shared__ float tile[32][129];
    int bid = blockIdx.x;          // b*64 + kt
    int kt = bid & 63;
    int b  = bid >> 6;
    int tx = threadIdx.x;
    const float* src = v + ((size_t)b * SKVL + (size_t)kt * 32) * DD;
#pragma unroll
    for (int i = 0; i < 16; ++i) {
        int e = i * 256 + tx;      // 4096 elems
        tile[e >> 7][e & 127] = src[e];
    }
    __syncthreads();
    ushort* dst = vt + ((size_t)bid << 12);
#pragma unroll
    for (int i = 0; i < 2; ++i) {
        int q = i * 256 + tx;      // 512 chunks: d(128) x cs'(4)
        int d = q >> 2;
        int csp = q & 3;
        int cs = csp ^ ((d >> 1) & 3);
        short8 o;
#pragma unroll
        for (int j = 0; j < 8; ++j) {
            int kv = (j >> 2) * 16 + cs * 4 + (j & 3);
            o[j] = (short)f2bf(tile[kv][d]);
        }
        *(short8*)(dst + d * 32 + csp * 8) = o;
    }
}

#define GLD_LDS16(gsrc, ldst) \
    __builtin_amdgcn_global_load_lds((const __attribute__((address_space(1))) uint32_t*)(gsrc), \
                                     (__attribute__((address_space(3))) uint32_t*)(ldst), 16, 0, 0)

// Flash attention fwd. Grid = B * SQ/64 = 512 blocks, 256 thr (4 waves).
// DUAL-STREAM: kv [0,1024) and [1024,2048) processed as two independent
// chains per wave (separate m/l/acc), interleaved by the scheduler to double
// ILP at fixed occupancy; states merged in-register at the end. K and V^T
// double-buffered per stream in LDS (64KB total), KVB=32 tiles.
__global__ __launch_bounds__(256, 2) void fattn(
    const ushort* __restrict__ qb, const ushort* __restrict__ kbt,
    const ushort* __restrict__ vbt, float* __restrict__ out)
{
    __shared__ short8 kls[2][2][512];   // [stream][buf][r*16 + chunk] 8KB each
    __shared__ short8 vls[2][2][512];   // [stream][buf][d*4 + chunk]  8KB each

    int bid = blockIdx.x;
    // XCD-bijective swizzle: 512 = 8 XCDs x 64 -> 2 batches' K/V per XCD L2.
    int swz = (bid & 7) * 64 + (bid >> 3);
    int b  = swz >> 5;
    int qt = swz & 31;
    int lane = threadIdx.x & 63;
    int w = threadIdx.x >> 6;
    int g = lane >> 4;
    int qi = lane & 15;
    int rx = qi & 7;
    int vx = g ^ ((qi >> 1) & 3);    // V chunk swizzle, constant per lane
    int qrow = qt * QBLK + w * 16 + qi;

    const char* kA = (const char*)(kbt + ((size_t)(b * 64) << 12));
    const char* vA = (const char*)(vbt + ((size_t)(b * 64) << 12));
    const char* kB = kA + ((size_t)NT << 13);   // stream B: tiles 32..63
    const char* vB = vA + ((size_t)NT << 13);

    // Q fragments: lane holds q=qi, d-slots ks*32 + g*8 + j. Shared by A and B.
    const ushort* qptr = qb + ((size_t)b * SQL + qrow) * DD;
    short8 qf[4];
#pragma unroll
    for (int ks = 0; ks < 4; ++ks)
        qf[ks] = *(const short8*)(qptr + ks * 32 + g * 8);

    f32x4 accA[8], accB[8];
#pragma unroll
    for (int i = 0; i < 8; ++i) { accA[i] = (f32x4)0.f; accB[i] = (f32x4)0.f; }
    float mA = -1e30f, lA = 0.f, mB = -1e30f, lB = 0.f;

    // prologue: stage tile 0 of both streams into buf 0
#pragma unroll
    for (int i = 0; i < 2; ++i) {
        int off = w * 2048 + i * 1024;
        GLD_LDS16(kA + off + lane * 16, (char*)&kls[0][0][0] + off);
        GLD_LDS16(vA + off + lane * 16, (char*)&vls[0][0][0] + off);
        GLD_LDS16(kB + off + lane * 16, (char*)&kls[1][0][0] + off);
        GLD_LDS16(vB + off + lane * 16, (char*)&vls[1][0][0] + off);
    }
    __syncthreads();

    for (int t = 0; t < NT; ++t) {
        int cur = t & 1, nxt = cur ^ 1;
        if (t + 1 < NT) {
            size_t toff = (size_t)(t + 1) << 13;
#pragma unroll
            for (int i = 0; i < 2; ++i) {
                int off = w * 2048 + i * 1024;
                GLD_LDS16(kA + toff + off + lane * 16, (char*)&kls[0][nxt][0] + off);
                GLD_LDS16(vA + toff + off + lane * 16, (char*)&vls[0][nxt][0] + off);
                GLD_LDS16(kB + toff + off + lane * 16, (char*)&kls[1][nxt][0] + off);
                GLD_LDS16(vB + toff + off + lane * 16, (char*)&vls[1][nxt][0] + off);
            }
        }
        // ======== two independent per-stream bodies (A then B in program
        // order; no cross-deps so the scheduler interleaves their chains) ====
#pragma unroll
        for (int s2 = 0; s2 < 2; ++s2) {
            f32x4* acc = s2 ? accB : accA;
            float& m = s2 ? mB : mA;
            float& lsum = s2 ? lB : lA;
            // ---- QK^T from LDS: S^T = mfma(K, Q) ----
            f32x4 st[2];
            __builtin_amdgcn_s_setprio(1);
#pragma unroll
            for (int sub = 0; sub < 2; ++sub) {
                f32x4 s = (f32x4)0.f;
                int r = sub * 16 + qi;
#pragma unroll
                for (int ks = 0; ks < 4; ++ks) {
                    short8 kf = kls[s2][cur][r * 16 + ((ks * 4 + g) ^ rx)];
                    s = __builtin_amdgcn_mfma_f32_16x16x32_bf16(kf, qf[ks], s, 0, 0, 0);
                }
                st[sub] = s;
            }
            __builtin_amdgcn_s_setprio(0);
            // ---- online softmax, defer-max; shfls only on the cold path ----
            float m0 = fmaxf(fmaxf(st[0][0], st[0][1]), fmaxf(st[0][2], st[0][3]));
            float m1 = fmaxf(fmaxf(st[1][0], st[1][1]), fmaxf(st[1][2], st[1][3]));
            float vmax = fmaxf(m0, m1);
            if (__any(vmax > m + 11.5f)) {
                float tmax = fmaxf(vmax, __shfl_xor(vmax, 16));
                tmax = fmaxf(tmax, __shfl_xor(tmax, 32));
                float mnew = fmaxf(m, tmax);
                float alpha = exp2f(m - mnew);
                m = mnew;
                lsum *= alpha;
#pragma unroll
                for (int i = 0; i < 8; ++i) {
                    acc[i][0] *= alpha; acc[i][1] *= alpha;
                    acc[i][2] *= alpha; acc[i][3] *= alpha;
                }
            }
            float pvv[8];
#pragma unroll
            for (int s = 0; s < 2; ++s) {
                pvv[s * 4 + 0] = exp2f(st[s][0] - m);
                pvv[s * 4 + 1] = exp2f(st[s][1] - m);
                pvv[s * 4 + 2] = exp2f(st[s][2] - m);
                pvv[s * 4 + 3] = exp2f(st[s][3] - m);
            }
            lsum += ((pvv[0] + pvv[1]) + (pvv[2] + pvv[3])) + ((pvv[4] + pvv[5]) + (pvv[6] + pvv[7]));
            union { short8 v; uint32_t u[4]; } P;
#pragma unroll
            for (int i = 0; i < 4; ++i)
                asm("v_cvt_pk_bf16_f32 %0, %1, %2" : "=v"(P.u[i]) : "v"(pvv[2 * i]), "v"(pvv[2 * i + 1]));
            // ---- PV from LDS: O^T += V^T * P^T (one MFMA per d-tile) ----
            __builtin_amdgcn_s_setprio(1);
#pragma unroll
            for (int dt = 0; dt < 8; ++dt) {
                int d = dt * 16 + qi;
                acc[dt] = __builtin_amdgcn_mfma_f32_16x16x32_bf16(
                    vls[s2][cur][d * 4 + vx], P.v, acc[dt], 0, 0, 0);
            }
            __builtin_amdgcn_s_setprio(0);
        }
        __syncthreads();   // stage(t+1) done (vmcnt0), reads of cur done
    }

    // ---- merge streams: O = (accA*fA + accB*fB) / (lA*fA + lB*fB) ----
    float mf = fmaxf(mA, mB);
    float fa = exp2f(mA - mf), fb = exp2f(mB - mf);
    float l = lA * fa + lB * fb;
    l += __shfl_xor(l, 16);
    l += __shfl_xor(l, 32);
    float inv = 1.f / l;
    float fia = fa * inv, fib = fb * inv;
    float* optr = out + ((size_t)b * SQL + qrow) * DD + g * 4;
#pragma unroll
    for (int dt = 0; dt < 8; ++dt) {
        f32x4 o;
        o[0] = accA[dt][0] * fia + accB[dt][0] * fib;
        o[1] = accA[dt][1] * fia + accB[dt][1] * fib;
        o[2] = accA[dt][2] * fia + accB[dt][2] * fib;
        o[3] = accA[dt][3] * fia + accB[dt][3] * fib;
        *(f32x4*)(optr + dt * 16) = o;
    }
}

extern "C" void kernel_launch(void* const* d_in, const int* in_sizes, int n_in,
                              void* d_out, int out_size, void* d_ws, size_t ws_size,
                              hipStream_t stream) {
    const float* q = (const float*)d_in[0];
    const float* k = (const float*)d_in[1];
    const float* v = (const float*)d_in[2];
    float* out = (float*)d_out;

    uint8_t* w = (uint8_t*)d_ws;
    size_t tsz = (size_t)NB * SQL * DD * sizeof(ushort);  // 8 MB per tensor
    ushort* qb  = (ushort*)w;
    ushort* kbt = (ushort*)(w + tsz);
    ushort* vbt = (ushort*)(w + 2 * tsz);

    float qscale = 1.4426950408889634f / sqrtf((float)DD);
    int n8 = NB * SQL * DD / 8;
    convert_scale_k<<<n8 / 256, 256, 0, stream>>>(q, qb, qscale);
    convert_k_tiled<<<NB * SKVL * 16 / 256, 256, 0, stream>>>(k, kbt);
    convert_vt_tiled<<<NB * (SKVL / 32), 256, 0, stream>>>(v, vbt);
    fattn<<<NB * (SQL / QBLK), 256, 0, stream>>>(qb, kbt, vbt, out);
}

// Round 10
// 149.197 us; speedup vs baseline: 1.5703x; 1.0441x over previous
//
#include <hip/hip_runtime.h>
#include <hip/hip_bf16.h>
#include <cstdint>
#include <cmath>

#define SQL 2048
#define SKVL 2048
#define DD 128
#define NB 16
#define QBLK 64
#define KVB 32
#define NT 32            // tiles per stream (two streams of 1024 kv each)

typedef __attribute__((ext_vector_type(8))) short short8;
typedef __attribute__((ext_vector_type(4))) float f32x4;

__device__ __forceinline__ ushort f2bf(float x) {
    union { float f; uint32_t u; } v; v.f = x;
    uint32_t r = v.u + 0x7FFFu + ((v.u >> 16) & 1u);
    return (ushort)(r >> 16);
}

// fp32 -> bf16 with scale folded in; 8 elements/thread. (Used for Q.)
__global__ void convert_scale_k(const float* __restrict__ in, ushort* __restrict__ out, float scale) {
    size_t i = (size_t)blockIdx.x * blockDim.x + threadIdx.x;
    const f32x4* p = (const f32x4*)in + i * 2;
    f32x4 a = p[0], b = p[1];
    short8 o;
    o[0] = (short)f2bf(a[0] * scale);
    o[1] = (short)f2bf(a[1] * scale);
    o[2] = (short)f2bf(a[2] * scale);
    o[3] = (short)f2bf(a[3] * scale);
    o[4] = (short)f2bf(b[0] * scale);
    o[5] = (short)f2bf(b[1] * scale);
    o[6] = (short)f2bf(b[2] * scale);
    o[7] = (short)f2bf(b[3] * scale);
    *((short8*)out + i) = o;
}

// K fp32 [B][SKV][128] -> tiled swizzled bf16 [B][SKV/32][32 rows x 128 cols].
// Within an 8KB tile: elem (r,c) -> r*128 + ((c>>3)^(r&7))*8 + (c&7).
__global__ void convert_k_tiled(const float* __restrict__ in, ushort* __restrict__ out) {
    int gid = blockIdx.x * blockDim.x + threadIdx.x;   // one 16B out-chunk (8 elems)
    int c16 = gid & 15;
    int rg  = gid >> 4;            // b*SKV + kv
    int r   = rg & 31;
    int tile = rg >> 5;            // b*64 + kt
    const f32x4* p = (const f32x4*)(in + (size_t)rg * DD + c16 * 8);
    f32x4 a = p[0], b = p[1];
    short8 o;
    o[0] = (short)f2bf(a[0]); o[1] = (short)f2bf(a[1]);
    o[2] = (short)f2bf(a[2]); o[3] = (short)f2bf(a[3]);
    o[4] = (short)f2bf(b[0]); o[5] = (short)f2bf(b[1]);
    o[6] = (short)f2bf(b[2]); o[7] = (short)f2bf(b[3]);
    int cs = c16 ^ (r & 7);
    *(short8*)(out + ((size_t)tile << 12) + r * 128 + cs * 8) = o;
}

// V fp32 [B][SKV][128] -> V^T tiled bf16 [B][SKV/32][128 d-rows x 32 kv].
// kv permuted to the PV mfma slot map: logical chunk cs elem j -> kv =
// (j>>2)*16 + cs*4 + (j&3); storage chunk cs' = cs ^ ((d>>1)&3) (XOR swizzle).
__global__ void convert_vt_tiled(const float* __restrict__ v, ushort* __restrict__ vt) {
    __shared__ float tile[32][129];
    int bid = blockIdx.x;          // b*64 + kt
    int kt = bid & 63;
    int b  = bid >> 6;
    int tx = threadIdx.x;
    const float* src = v + ((size_t)b * SKVL + (size_t)kt * 32) * DD;
#pragma unroll
    for (int i = 0; i < 16; ++i) {
        int e = i * 256 + tx;      // 4096 elems
        tile[e >> 7][e & 127] = src[e];
    }
    __syncthreads();
    ushort* dst = vt + ((size_t)bid << 12);
#pragma unroll
    for (int i = 0; i < 2; ++i) {
        int q = i * 256 + tx;      // 512 chunks: d(128) x cs'(4)
        int d = q >> 2;
        int csp = q & 3;
        int cs = csp ^ ((d >> 1) & 3);
        short8 o;
#pragma unroll
        for (int j = 0; j < 8; ++j) {
            int kv = (j >> 2) * 16 + cs * 4 + (j & 3);
            o[j] = (short)f2bf(tile[kv][d]);
        }
        *(short8*)(dst + d * 32 + csp * 8) = o;
    }
}

#define GLD_LDS16(gsrc, ldst) \
    __builtin_amdgcn_global_load_lds((const __attribute__((address_space(1))) uint32_t*)(gsrc), \
                                     (__attribute__((address_space(3))) uint32_t*)(ldst), 16, 0, 0)

// Flash attention fwd. Grid = B * SQ/64 = 512 blocks, 512 thr (8 waves):
// waves = 4 q-groups x 2 kv-half-streams -> 2 blocks/CU x 8 waves =
// 16 waves/CU = 4/SIMD (doubled latency hiding vs 4-wave blocks).
// Each stream's K/V^T double-buffered in LDS (64KB total), KVB=32 tiles.
// Streams merged in LDS at the end (no global partials).
__global__ __launch_bounds__(512, 4) void fattn(
    const ushort* __restrict__ qb, const ushort* __restrict__ kbt,
    const ushort* __restrict__ vbt, float* __restrict__ out)
{
    __shared__ short8 kls[2][2][512];   // [stream][buf][r*16 + chunk] 8KB each
    __shared__ short8 vls[2][2][512];   // [stream][buf][d*4 + chunk]  8KB each

    int bid = blockIdx.x;
    // XCD-bijective swizzle: 512 = 8 XCDs x 64 -> 2 batches' K/V per XCD L2.
    int swz = (bid & 7) * 64 + (bid >> 3);
    int b  = swz >> 5;
    int qt = swz & 31;
    int lane = threadIdx.x & 63;
    int w = threadIdx.x >> 6;        // 0..7
    int s2 = w >> 2;                 // kv-half stream
    int qg = w & 3;                  // q-group
    int g = lane >> 4;
    int qi = lane & 15;
    int rx = qi & 7;
    int vx = g ^ ((qi >> 1) & 3);    // V chunk swizzle, constant per lane
    int qrow = qt * QBLK + qg * 16 + qi;

    const char* kS0 = (const char*)(kbt + ((size_t)(b * 64) << 12));
    const char* vS0 = (const char*)(vbt + ((size_t)(b * 64) << 12));
    const char* kS1 = kS0 + ((size_t)NT << 13);   // stream B: tiles 32..63
    const char* vS1 = vS0 + ((size_t)NT << 13);

    // staging role: region r = w>>1 in {K0,V0,K1,V1}, half = w&1 (4KB each)
    int rreg = w >> 1;
    const char* gbase = (rreg == 0) ? kS0 : (rreg == 1) ? vS0 : (rreg == 2) ? kS1 : vS1;
    char* l0 = (rreg == 0) ? (char*)kls[0][0] : (rreg == 1) ? (char*)vls[0][0]
             : (rreg == 2) ? (char*)kls[1][0] : (char*)vls[1][0];
    char* l1 = (rreg == 0) ? (char*)kls[0][1] : (rreg == 1) ? (char*)vls[0][1]
             : (rreg == 2) ? (char*)kls[1][1] : (char*)vls[1][1];
    int soff = (w & 1) * 4096;

    // Q fragments: lane holds q=qi, d-slots ks*32 + g*8 + j.
    const ushort* qptr = qb + ((size_t)b * SQL + qrow) * DD;
    short8 qf[4];
#pragma unroll
    for (int ks = 0; ks < 4; ++ks)
        qf[ks] = *(const short8*)(qptr + ks * 32 + g * 8);

    f32x4 acc[8];
#pragma unroll
    for (int i = 0; i < 8; ++i) acc[i] = (f32x4)0.f;
    float m = -1e30f, lsum = 0.f;

    // prologue: stage tile 0 of both streams into buf 0 (each wave its 4KB)
#pragma unroll
    for (int i = 0; i < 4; ++i)
        GLD_LDS16(gbase + soff + i * 1024 + lane * 16, l0 + soff + i * 1024);
    __syncthreads();

    const short8* kst = kls[s2][0];   // stream bases (buf stride 512 short8)
    const short8* vst = vls[s2][0];

    for (int t = 0; t < NT; ++t) {
        int cur = t & 1, nxt = cur ^ 1;
        if (t + 1 < NT) {
            size_t toff = (size_t)(t + 1) << 13;
            char* ld = nxt ? l1 : l0;
#pragma unroll
            for (int i = 0; i < 4; ++i)
                GLD_LDS16(gbase + toff + soff + i * 1024 + lane * 16, ld + soff + i * 1024);
        }
        const short8* kcur = kst + cur * 512;
        const short8* vcur = vst + cur * 512;
        // ---- QK^T from LDS: S^T = mfma(K, Q) ----
        f32x4 st[2];
        __builtin_amdgcn_s_setprio(1);
#pragma unroll
        for (int sub = 0; sub < 2; ++sub) {
            f32x4 s = (f32x4)0.f;
            int r = sub * 16 + qi;
#pragma unroll
            for (int ks = 0; ks < 4; ++ks) {
                short8 kf = kcur[r * 16 + ((ks * 4 + g) ^ rx)];
                s = __builtin_amdgcn_mfma_f32_16x16x32_bf16(kf, qf[ks], s, 0, 0, 0);
            }
            st[sub] = s;
        }
        __builtin_amdgcn_s_setprio(0);
        // ---- online softmax, defer-max; shfls only on the cold path ----
        float m0 = fmaxf(fmaxf(st[0][0], st[0][1]), fmaxf(st[0][2], st[0][3]));
        float m1 = fmaxf(fmaxf(st[1][0], st[1][1]), fmaxf(st[1][2], st[1][3]));
        float vmax = fmaxf(m0, m1);
        if (__any(vmax > m + 11.5f)) {
            float tmax = fmaxf(vmax, __shfl_xor(vmax, 16));
            tmax = fmaxf(tmax, __shfl_xor(tmax, 32));
            float mnew = fmaxf(m, tmax);
            float alpha = exp2f(m - mnew);
            m = mnew;
            lsum *= alpha;
#pragma unroll
            for (int i = 0; i < 8; ++i) {
                acc[i][0] *= alpha; acc[i][1] *= alpha;
                acc[i][2] *= alpha; acc[i][3] *= alpha;
            }
        }
        float pvv[8];
#pragma unroll
        for (int s = 0; s < 2; ++s) {
            pvv[s * 4 + 0] = exp2f(st[s][0] - m);
            pvv[s * 4 + 1] = exp2f(st[s][1] - m);
            pvv[s * 4 + 2] = exp2f(st[s][2] - m);
            pvv[s * 4 + 3] = exp2f(st[s][3] - m);
        }
        lsum += ((pvv[0] + pvv[1]) + (pvv[2] + pvv[3])) + ((pvv[4] + pvv[5]) + (pvv[6] + pvv[7]));
        union { short8 v; uint32_t u[4]; } P;
#pragma unroll
        for (int i = 0; i < 4; ++i)
            asm("v_cvt_pk_bf16_f32 %0, %1, %2" : "=v"(P.u[i]) : "v"(pvv[2 * i]), "v"(pvv[2 * i + 1]));
        // ---- PV from LDS: O^T += V^T * P^T (one MFMA per d-tile) ----
        __builtin_amdgcn_s_setprio(1);
#pragma unroll
        for (int dt = 0; dt < 8; ++dt) {
            int d = dt * 16 + qi;
            acc[dt] = __builtin_amdgcn_mfma_f32_16x16x32_bf16(
                vcur[d * 4 + vx], P.v, acc[dt], 0, 0, 0);
        }
        __builtin_amdgcn_s_setprio(0);
        __syncthreads();   // stage(t+1) done (vmcnt0), reads of cur done
    }

    // ---- merge kv-half streams in LDS: waves 4-7 publish, waves 0-3 combine ----
    float* mb = (float*)&kls[0][0][0];   // 4 waves x 64 lanes x 36 f32 = 36KB
    if (w >= 4) {
        int base = ((w - 4) * 64 + lane) * 36;
#pragma unroll
        for (int dt = 0; dt < 8; ++dt)
            *(f32x4*)(mb + base + dt * 4) = acc[dt];
        mb[base + 32] = m;
        mb[base + 33] = lsum;
    }
    __syncthreads();
    if (w < 4) {
        int base = (w * 64 + lane) * 36;
        float mB = mb[base + 32], lB = mb[base + 33];
        float mf = fmaxf(m, mB);
        float fa = exp2f(m - mf), fb = exp2f(mB - mf);
        float l = lsum * fa + lB * fb;
        l += __shfl_xor(l, 16);
        l += __shfl_xor(l, 32);
        float inv = 1.f / l;
        float fia = fa * inv, fib = fb * inv;
        float* optr = out + ((size_t)b * SQL + qrow) * DD + g * 4;
#pragma unroll
        for (int dt = 0; dt < 8; ++dt) {
            f32x4 ob = *(const f32x4*)(mb + base + dt * 4);
            f32x4 o;
            o[0] = acc[dt][0] * fia + ob[0] * fib;
            o[1] = acc[dt][1] * fia + ob[1] * fib;
            o[2] = acc[dt][2] * fia + ob[2] * fib;
            o[3] = acc[dt][3] * fia + ob[3] * fib;
            *(f32x4*)(optr + dt * 16) = o;
        }
    }
}

extern "C" void kernel_launch(void* const* d_in, const int* in_sizes, int n_in,
                              void* d_out, int out_size, void* d_ws, size_t ws_size,
                              hipStream_t stream) {
    const float* q = (const float*)d_in[0];
    const float* k = (const float*)d_in[1];
    const float* v = (const float*)d_in[2];
    float* out = (float*)d_out;

    uint8_t* w = (uint8_t*)d_ws;
    size_t tsz = (size_t)NB * SQL * DD * sizeof(ushort);  // 8 MB per tensor
    ushort* qb  = (ushort*)w;
    ushort* kbt = (ushort*)(w + tsz);
    ushort* vbt = (ushort*)(w + 2 * tsz);

    float qscale = 1.4426950408889634f / sqrtf((float)DD);
    int n8 = NB * SQL * DD / 8;
    convert_scale_k<<<n8 / 256, 256, 0, stream>>>(q, qb, qscale);
    convert_k_tiled<<<NB * SKVL * 16 / 256, 256, 0, stream>>>(k, kbt);
    convert_vt_tiled<<<NB * (SKVL / 32), 256, 0, stream>>>(v, vbt);
    fattn<<<NB * (SQL / QBLK), 512, 0, stream>>>(qb, kbt, vbt, out);
}